// Round 3
// baseline (702.701 us; speedup 1.0000x reference)
//
#include <hip/hip_runtime.h>
#include <hip/hip_cooperative_groups.h>
#include <hip/hip_bf16.h>
#include <stdint.h>

namespace cg = cooperative_groups;

#define DEV __device__ __forceinline__

typedef __attribute__((ext_vector_type(8))) short short8;   // 8 bf16 (4 VGPRs)
typedef __attribute__((ext_vector_type(4))) float f32x4;    // MFMA acc

#define TWO_LOG2E 2.8853900817779268f   // 2*log2(e): exp(2x) == exp2(x*TWO_LOG2E)

// ---------------------------------------------------------------- helpers
DEV unsigned short f2bf(float f) {           // fp32 -> bf16, RNE
  uint32_t u = __float_as_uint(f);
  u += 0x7FFFu + ((u >> 16) & 1u);
  return (unsigned short)(u >> 16);
}

DEV uint2 pk4(float4 f) {                    // 4 fp32 -> 4 bf16 (packed cvt)
  union { __hip_bfloat162 h; unsigned u; } a, b;
  a.h = __float22bfloat162_rn(make_float2(f.x, f.y));
  b.h = __float22bfloat162_rn(make_float2(f.z, f.w));
  return make_uint2(a.u, b.u);
}

DEV short8 mk8(uint2 lo, uint2 hi) {
  union { short8 s; uint4 u; } t;
  t.u = make_uint4(lo.x, lo.y, hi.x, hi.y);
  return t.s;
}

DEV uint32_t rotl32(uint32_t x, int r) { return (x << r) | (x >> (32 - r)); }

// JAX Threefry-2x32 with key = (0, 42)  (jax.random.key(42))
DEV void threefry_0_42(uint32_t x0, uint32_t x1, uint32_t& o0, uint32_t& o1) {
  const uint32_t ks0 = 0u, ks1 = 42u, ks2 = 0x1BD11BDAu ^ 42u;
  x0 += ks0; x1 += ks1;
#define TFR(r) { x0 += x1; x1 = rotl32(x1, (r)); x1 ^= x0; }
  TFR(13) TFR(15) TFR(26) TFR(6)  x0 += ks1; x1 += ks2 + 1u;
  TFR(17) TFR(29) TFR(16) TFR(24) x0 += ks2; x1 += ks0 + 2u;
  TFR(13) TFR(15) TFR(26) TFR(6)  x0 += ks0; x1 += ks1 + 3u;
  TFR(17) TFR(29) TFR(16) TFR(24) x0 += ks1; x1 += ks2 + 4u;
  TFR(13) TFR(15) TFR(26) TFR(6)  x0 += ks2; x1 += ks0 + 5u;
#undef TFR
  o0 = x0; o1 = x1;
}

DEV float wredmax(float v) {
#pragma unroll
  for (int off = 32; off > 0; off >>= 1) v = fmaxf(v, __shfl_xor(v, off));
  return v;
}
DEV float wredsum(float v) {
#pragma unroll
  for (int off = 32; off > 0; off >>= 1) v += __shfl_xor(v, off);
  return v;
}

// ================================================================ phase 0: weight transposes
DEV void ph_transpose(int b, int tid, char* smem,
                      const float* Wctx, const float* Wq, const float* Wout,
                      unsigned short* WctxT, unsigned short* WqT, unsigned short* WoutT) {
  float (*tile)[65] = (float(*)[65])smem;
  const float* src; unsigned short* dst; int R, C, br, bc;
  if (b < 8)       { src = Wctx; dst = WctxT; R = 512;  C = 64;  br = b * 64;       bc = 0; }
  else if (b < 16) { src = Wq;   dst = WqT;   R = 512;  C = 64;  br = (b - 8) * 64; bc = 0; }
  else { int i = b - 16; src = Wout; dst = WoutT; R = 1024; C = 512; br = (i & 15) * 64; bc = (i >> 4) * 64; }
  const int lr = tid >> 4, lc4 = (tid & 15) * 4;
#pragma unroll
  for (int i = 0; i < 4; ++i) {
    float4 vv = *(const float4*)(src + (long)(br + lr + i * 16) * C + bc + lc4);
    tile[lr + i * 16][lc4 + 0] = vv.x;
    tile[lr + i * 16][lc4 + 1] = vv.y;
    tile[lr + i * 16][lc4 + 2] = vv.z;
    tile[lr + i * 16][lc4 + 3] = vv.w;
  }
  __syncthreads();
#pragma unroll
  for (int i = 0; i < 4; ++i) {
    int crow = lr + i * 16;
    ushort4 o;
    o.x = f2bf(tile[lc4 + 0][crow]);
    o.y = f2bf(tile[lc4 + 1][crow]);
    o.z = f2bf(tile[lc4 + 2][crow]);
    o.w = f2bf(tile[lc4 + 3][crow]);
    *(ushort4*)(dst + (long)(bc + crow) * R + br + lc4) = o;
  }
}

// ================================================================ phase 1a: uh / wq GEMM tile
DEV void ph_uhwq(int t, int tid, char* smem,
                 const float* mb, const float* input,
                 const unsigned short* WctxT, const unsigned short* WqT,
                 float* uhT, float* wqo) {
  unsigned short (*As)[32] = (unsigned short(*)[32])smem;
  unsigned short (*Bs)[32] = (unsigned short(*)[32])(smem + 4096);
  const float* A; const unsigned short* BT; int mbase;
  if (t < 256) { A = mb;    BT = WctxT; mbase = t * 64; }
  else         { A = input; BT = WqT;   mbase = (t - 256) * 64; }
  const int srow = tid >> 2, kc = tid & 3;
  const int scol = ((kc ^ (srow & 3)) * 8);
  const int wave = tid >> 6, lane = tid & 63;
  const int wm = (wave >> 1) * 32, wn = (wave & 1) * 32;
  const int q = lane >> 4, r = lane & 15;
  const int c0 = ((q ^ (r & 3)) * 8);
  const float* ap = A + (long)(mbase + srow) * 512 + kc * 8;
  const unsigned short* bp = BT + (long)srow * 512 + kc * 8;
  f32x4 acc[2][2];
#pragma unroll
  for (int i = 0; i < 2; ++i)
#pragma unroll
    for (int j = 0; j < 2; ++j) acc[i][j] = (f32x4){0.f, 0.f, 0.f, 0.f};
  float4 fa0 = *(const float4*)(ap);
  float4 fa1 = *(const float4*)(ap + 4);
  uint4 fb = *(const uint4*)(bp);
  for (int k0 = 0; k0 < 512; k0 += 32) {
    uint2 p0 = pk4(fa0), p1 = pk4(fa1);
    *(uint4*)&As[srow][scol] = make_uint4(p0.x, p0.y, p1.x, p1.y);
    *(uint4*)&Bs[srow][scol] = fb;
    __syncthreads();
    if (k0 + 32 < 512) {
      fa0 = *(const float4*)(ap + k0 + 32);
      fa1 = *(const float4*)(ap + k0 + 36);
      fb = *(const uint4*)(bp + k0 + 32);
    }
    short8 a0 = *(const short8*)&As[wm + r][c0];
    short8 a1 = *(const short8*)&As[wm + 16 + r][c0];
    short8 b0 = *(const short8*)&Bs[wn + r][c0];
    short8 b1 = *(const short8*)&Bs[wn + 16 + r][c0];
    acc[0][0] = __builtin_amdgcn_mfma_f32_16x16x32_bf16(a0, b0, acc[0][0], 0, 0, 0);
    acc[0][1] = __builtin_amdgcn_mfma_f32_16x16x32_bf16(a0, b1, acc[0][1], 0, 0, 0);
    acc[1][0] = __builtin_amdgcn_mfma_f32_16x16x32_bf16(a1, b0, acc[1][0], 0, 0, 0);
    acc[1][1] = __builtin_amdgcn_mfma_f32_16x16x32_bf16(a1, b1, acc[1][1], 0, 0, 0);
    __syncthreads();
  }
#pragma unroll
  for (int i2 = 0; i2 < 2; ++i2)
#pragma unroll
    for (int j2 = 0; j2 < 2; ++j2) {
      int gcol = wn + j2 * 16 + r;
      int m = mbase + wm + i2 * 16 + q * 4;
      if (t < 256) {                                   // transposed: uhT[n][d][s]
        int n = m >> 10, s0 = m & 1023;
        float4 o;
        o.x = acc[i2][j2][0] * TWO_LOG2E;
        o.y = acc[i2][j2][1] * TWO_LOG2E;
        o.z = acc[i2][j2][2] * TWO_LOG2E;
        o.w = acc[i2][j2][3] * TWO_LOG2E;
        *(float4*)(uhT + (long)n * 65536 + (long)gcol * 1024 + s0) = o;
      } else {
#pragma unroll
        for (int reg = 0; reg < 4; ++reg)
          wqo[(long)(m + reg) * 64 + gcol] = acc[i2][j2][reg] * TWO_LOG2E;
      }
    }
}

// ================================================================ phase 1b: P = input @ W_top + b
DEV void ph_pre(int tt, int tid, char* smem,
                const float* input, const unsigned short* WoutT,
                const float* bout, float* P) {
  unsigned short (*As)[32] = (unsigned short(*)[32])smem;
  unsigned short (*Bs)[32] = (unsigned short(*)[32])(smem + 4096);
  const int mbase = (tt >> 4) * 64, nbase = (tt & 15) * 32;
  const int srow = tid >> 2, kc = tid & 3;
  const int scol = ((kc ^ (srow & 3)) * 8);
  const int wave = tid >> 6, lane = tid & 63;
  const int wm = (wave >> 1) * 32, wn = (wave & 1) * 16;
  const int q = lane >> 4, r = lane & 15;
  const int c0 = ((q ^ (r & 3)) * 8);
  const float* ap = input + (long)(mbase + srow) * 512 + kc * 8;
  const int brow = (tid & 127) >> 2;
  const unsigned short* bp = WoutT + (long)(nbase + brow) * 1024 + kc * 8;
  f32x4 acc[2];
  acc[0] = (f32x4){0.f, 0.f, 0.f, 0.f};
  acc[1] = (f32x4){0.f, 0.f, 0.f, 0.f};
  float4 fa0 = *(const float4*)(ap);
  float4 fa1 = *(const float4*)(ap + 4);
  uint4 fb;
  if (tid < 128) fb = *(const uint4*)(bp);
  for (int k0 = 0; k0 < 512; k0 += 32) {
    uint2 p0 = pk4(fa0), p1 = pk4(fa1);
    *(uint4*)&As[srow][scol] = make_uint4(p0.x, p0.y, p1.x, p1.y);
    if (tid < 128) *(uint4*)&Bs[brow][(kc ^ (brow & 3)) * 8] = fb;
    __syncthreads();
    int kn = k0 + 32;
    if (kn < 512) {
      fa0 = *(const float4*)(ap + kn);
      fa1 = *(const float4*)(ap + kn + 4);
      if (tid < 128) fb = *(const uint4*)(bp + kn);
    }
    short8 a0 = *(const short8*)&As[wm + r][c0];
    short8 a1 = *(const short8*)&As[wm + 16 + r][c0];
    short8 b0 = *(const short8*)&Bs[wn + r][c0];
    acc[0] = __builtin_amdgcn_mfma_f32_16x16x32_bf16(a0, b0, acc[0], 0, 0, 0);
    acc[1] = __builtin_amdgcn_mfma_f32_16x16x32_bf16(a1, b0, acc[1], 0, 0, 0);
    __syncthreads();
  }
#pragma unroll
  for (int i2 = 0; i2 < 2; ++i2) {
    int gcol = nbase + wn + r;
    float bb = bout[gcol];
#pragma unroll
    for (int reg = 0; reg < 4; ++reg) {
      int grow = mbase + wm + i2 * 16 + q * 4 + reg;
      P[(long)grow * 512 + gcol] = acc[i2][reg] + bb;
    }
  }
}

// ================================================================ phase 2 helper: softmax + gumbel + writes
DEV void softmax_gumbel_write(float* lsc, int nt, int tid, float* red,
                              unsigned short* alpha_bf, unsigned short* yal_bf) {
  const int wv = tid >> 6, ln = tid & 63;
  float m = fmaxf(fmaxf(lsc[0], lsc[1]), fmaxf(lsc[2], lsc[3]));
  m = wredmax(m);
  if (ln == 0) red[wv] = m;
  __syncthreads();
  m = fmaxf(fmaxf(red[0], red[1]), fmaxf(red[2], red[3]));
  __syncthreads();
  float ss = 0.f;
#pragma unroll
  for (int i = 0; i < 4; ++i) ss += __expf(lsc[i] - m);
  ss = wredsum(ss);
  if (ln == 0) red[wv] = ss;
  __syncthreads();
  ss = red[0] + red[1] + red[2] + red[3];
  const float logl = __logf(ss);
  __syncthreads();

  const uint32_t jbase = (uint32_t)nt * 1024u + (uint32_t)tid * 4u;
  float ys[4];
  float4 av;
#pragma unroll
  for (int i = 0; i < 4; ++i) {
    float la = lsc[i] - m - logl;
    ((float*)&av)[i] = __expf(la);
    uint32_t o0, o1;
    threefry_0_42(0u, jbase + i, o0, o1);
    uint32_t bits = o0 ^ o1;
    float u = __uint_as_float((bits >> 9) | 0x3f800000u) - 1.0f;
    float g = -__logf(-__logf(u + 1e-20f) + 1e-20f);
    ys[i] = (la + g) * 2.0f;                           // /TEMPERATURE (0.5)
  }
  {
    uint2 pa = pk4(av);
    *(uint2*)(alpha_bf + (long)nt * 1024 + tid * 4) = pa;
  }
  float m2 = fmaxf(fmaxf(ys[0], ys[1]), fmaxf(ys[2], ys[3]));
  m2 = wredmax(m2);
  if (ln == 0) red[wv] = m2;
  __syncthreads();
  m2 = fmaxf(fmaxf(red[0], red[1]), fmaxf(red[2], red[3]));
  __syncthreads();
  float s2 = 0.f;
  float4 ye;
#pragma unroll
  for (int i = 0; i < 4; ++i) { ((float*)&ye)[i] = __expf(ys[i] - m2); s2 += ((float*)&ye)[i]; }
  s2 = wredsum(s2);
  if (ln == 0) red[wv] = s2;
  __syncthreads();
  s2 = red[0] + red[1] + red[2] + red[3];
  const float rinv = __fdividef(1.f, s2);
  ye.x *= rinv; ye.y *= rinv; ye.z *= rinv; ye.w *= rinv;
  {
    uint2 py = pk4(ye);
    *(uint2*)(yal_bf + (long)nt * 1024 + tid * 4) = py;
  }
  __syncthreads();   // guard red[] reuse by caller's next invocation
}

// ================================================================ phase 2: scores pair (nt0, nt0+512)
DEV void ph_scores_pair(int nt0, int tid, char* smem,
                        const float* uhT, const float* wqo, const float* vvec,
                        unsigned short* alpha_bf, unsigned short* yal_bf) {
  float* wvs0 = (float*)smem;         // 64
  float* wvs1 = wvs0 + 64;            // 64
  float* vvs  = wvs1 + 64;            // 64
  float* red  = vvs + 64;             // 4
  const int nt1 = nt0 + 512;
  const int n0 = nt0 >> 6, n1 = nt1 >> 6;
  if (tid < 64) {
    wvs0[tid] = wqo[nt0 * 64 + tid];
    wvs1[tid] = wqo[nt1 * 64 + tid];
    vvs[tid]  = vvec[tid];
  }
  __syncthreads();
  float sumv = 0.f;
#pragma unroll
  for (int d = 0; d < 64; d += 4) {
    float4 vv = *(const float4*)&vvs[d];
    sumv += vv.x + vv.y + vv.z + vv.w;
  }
  const float* un0 = uhT + (long)n0 * 65536 + tid * 4;
  const float* un1 = uhT + (long)n1 * 65536 + tid * 4;
  float4 r0 = make_float4(0.f, 0.f, 0.f, 0.f);
  float4 r1 = make_float4(0.f, 0.f, 0.f, 0.f);
  for (int db = 0; db < 64; db += 4) {
    float4 ua[4], ub[4];
#pragma unroll
    for (int j = 0; j < 4; ++j) {
      ua[j] = *(const float4*)(un0 + (long)(db + j) * 1024);
      ub[j] = *(const float4*)(un1 + (long)(db + j) * 1024);
    }
#pragma unroll
    for (int j = 0; j < 4; ++j) {
      float w0 = wvs0[db + j], w1 = wvs1[db + j], vvj = vvs[db + j];
      r0.x = fmaf(vvj, __builtin_amdgcn_rcpf(1.f + __builtin_amdgcn_exp2f(ua[j].x + w0)), r0.x);
      r0.y = fmaf(vvj, __builtin_amdgcn_rcpf(1.f + __builtin_amdgcn_exp2f(ua[j].y + w0)), r0.y);
      r0.z = fmaf(vvj, __builtin_amdgcn_rcpf(1.f + __builtin_amdgcn_exp2f(ua[j].z + w0)), r0.z);
      r0.w = fmaf(vvj, __builtin_amdgcn_rcpf(1.f + __builtin_amdgcn_exp2f(ua[j].w + w0)), r0.w);
      r1.x = fmaf(vvj, __builtin_amdgcn_rcpf(1.f + __builtin_amdgcn_exp2f(ub[j].x + w1)), r1.x);
      r1.y = fmaf(vvj, __builtin_amdgcn_rcpf(1.f + __builtin_amdgcn_exp2f(ub[j].y + w1)), r1.y);
      r1.z = fmaf(vvj, __builtin_amdgcn_rcpf(1.f + __builtin_amdgcn_exp2f(ub[j].z + w1)), r1.z);
      r1.w = fmaf(vvj, __builtin_amdgcn_rcpf(1.f + __builtin_amdgcn_exp2f(ub[j].w + w1)), r1.w);
    }
  }
  float lsc0[4], lsc1[4];
  lsc0[0] = fmaf(-2.f, r0.x, sumv); lsc0[1] = fmaf(-2.f, r0.y, sumv);
  lsc0[2] = fmaf(-2.f, r0.z, sumv); lsc0[3] = fmaf(-2.f, r0.w, sumv);
  lsc1[0] = fmaf(-2.f, r1.x, sumv); lsc1[1] = fmaf(-2.f, r1.y, sumv);
  lsc1[2] = fmaf(-2.f, r1.z, sumv); lsc1[3] = fmaf(-2.f, r1.w, sumv);
  softmax_gumbel_write(lsc0, nt0, tid, red, alpha_bf, yal_bf);
  softmax_gumbel_write(lsc1, nt1, tid, red, alpha_bf, yal_bf);
}

// ================================================================ phase 3: ctx tile (one n, dbase, vt)
DEV void ph_ctx(int n, int dbase, int vt, int tid, char* smem,
                const unsigned short* alpha_bf, const unsigned short* yal_bf,
                const float* mb, unsigned short* ctxb) {
  unsigned short (*As)[32] = (unsigned short(*)[32])smem;
  const int srow = tid >> 2, kc = tid & 3;
  const int scol = ((kc ^ (srow & 3)) * 8);
  const int wave = tid >> 6, lane = tid & 63;
  const int wm = (wave >> 1) * 32, wn = (wave & 1) * 16;
  const int q = lane >> 4, r = lane & 15;
  const int c0 = ((q ^ (r & 3)) * 8);
  const unsigned short* Ab = (vt ? yal_bf : alpha_bf) + (long)n * 65536 + (long)srow * 1024 + kc * 8;
  const float* bcol = mb + (long)n * 524288 + dbase + wn + r;
  f32x4 acc[2];
  acc[0] = (f32x4){0.f, 0.f, 0.f, 0.f};
  acc[1] = (f32x4){0.f, 0.f, 0.f, 0.f};
  uint4 fa = *(const uint4*)(Ab);
  float bv[8];
#pragma unroll
  for (int j = 0; j < 8; ++j) bv[j] = bcol[(long)(q * 8 + j) * 512];
  for (int k0 = 0; k0 < 1024; k0 += 32) {
    *(uint4*)&As[srow][scol] = fa;
    __syncthreads();
    float4 blo = make_float4(bv[0], bv[1], bv[2], bv[3]);
    float4 bhi = make_float4(bv[4], bv[5], bv[6], bv[7]);
    short8 b0 = mk8(pk4(blo), pk4(bhi));
    if (k0 + 32 < 1024) {
      fa = *(const uint4*)(Ab + k0 + 32);
#pragma unroll
      for (int j = 0; j < 8; ++j) bv[j] = bcol[(long)(k0 + 32 + q * 8 + j) * 512];
    }
    short8 a0 = *(const short8*)&As[wm + r][c0];
    short8 a1 = *(const short8*)&As[wm + 16 + r][c0];
    acc[0] = __builtin_amdgcn_mfma_f32_16x16x32_bf16(a0, b0, acc[0], 0, 0, 0);
    acc[1] = __builtin_amdgcn_mfma_f32_16x16x32_bf16(a1, b0, acc[1], 0, 0, 0);
    __syncthreads();
  }
#pragma unroll
  for (int i2 = 0; i2 < 2; ++i2) {
    int gcol = dbase + wn + r;
#pragma unroll
    for (int reg = 0; reg < 4; ++reg) {
      long grow = (long)vt * 1024 + n * 64 + wm + i2 * 16 + q * 4 + reg;
      ctxb[grow * 512 + gcol] = f2bf(acc[i2][reg]);
    }
  }
}

// ================================================================ phase 4: out tile
DEV void ph_out(int mbase, int nbase, int tid, char* smem,
                const unsigned short* ctxb, const unsigned short* WoutT,
                const float* P, float* out) {
  unsigned short (*As)[32] = (unsigned short(*)[32])smem;
  unsigned short (*Bs)[32] = (unsigned short(*)[32])(smem + 4096);
  const int srow = tid >> 2, kc = tid & 3;
  const int scol = ((kc ^ (srow & 3)) * 8);
  const int wave = tid >> 6, lane = tid & 63;
  const int wm = (wave >> 1) * 32, wn = (wave & 1) * 16;
  const int q = lane >> 4, r = lane & 15;
  const int c0 = ((q ^ (r & 3)) * 8);
  const unsigned short* ap = ctxb + (long)(mbase + srow) * 512 + kc * 8;
  const int brow = (tid & 127) >> 2;
  const unsigned short* bp = WoutT + (long)(nbase + brow) * 1024 + 512 + kc * 8;
  f32x4 acc[2];
#pragma unroll
  for (int i2 = 0; i2 < 2; ++i2) {
    int pcol = nbase + wn + r;
#pragma unroll
    for (int reg = 0; reg < 4; ++reg) {
      int prow = (mbase + wm + i2 * 16 + q * 4 + reg) & 1023;
      acc[i2][reg] = P[(long)prow * 512 + pcol];
    }
  }
  uint4 fa = *(const uint4*)(ap);
  uint4 fb;
  if (tid < 128) fb = *(const uint4*)(bp);
  for (int k0 = 0; k0 < 512; k0 += 32) {
    *(uint4*)&As[srow][scol] = fa;
    if (tid < 128) *(uint4*)&Bs[brow][(kc ^ (brow & 3)) * 8] = fb;
    __syncthreads();
    int kn = k0 + 32;
    if (kn < 512) {
      fa = *(const uint4*)(ap + kn);
      if (tid < 128) fb = *(const uint4*)(bp + kn);
    }
    short8 a0 = *(const short8*)&As[wm + r][c0];
    short8 a1 = *(const short8*)&As[wm + 16 + r][c0];
    short8 b0 = *(const short8*)&Bs[wn + r][c0];
    acc[0] = __builtin_amdgcn_mfma_f32_16x16x32_bf16(a0, b0, acc[0], 0, 0, 0);
    acc[1] = __builtin_amdgcn_mfma_f32_16x16x32_bf16(a1, b0, acc[1], 0, 0, 0);
    __syncthreads();
  }
#pragma unroll
  for (int i2 = 0; i2 < 2; ++i2) {
    int gcol = nbase + wn + r;
#pragma unroll
    for (int reg = 0; reg < 4; ++reg) {
      int grow = mbase + wm + i2 * 16 + q * 4 + reg;
      float z = acc[i2][reg];
      float rc = __builtin_amdgcn_rcpf(1.f + __builtin_amdgcn_exp2f(z * TWO_LOG2E));
      out[(long)grow * 512 + gcol] = fmaf(-2.f, rc, 1.f);
    }
  }
}

// ================================================================ mega (cooperative)
__global__ __launch_bounds__(256, 2) void mega(const float* __restrict__ input,
                                               const float* __restrict__ mb,
                                               const float* __restrict__ Wq,
                                               const float* __restrict__ Wctx,
                                               const float* __restrict__ vvec,
                                               const float* __restrict__ Wout,
                                               const float* __restrict__ bout,
                                               float* __restrict__ out,
                                               float* __restrict__ ws) {
  float* uhT = ws;
  float* wqo = ws + 1048576;
  unsigned short* alpha_bf = (unsigned short*)(ws + 1114112);
  unsigned short* yal_bf   = (unsigned short*)(ws + 1638400);
  unsigned short* WctxT = (unsigned short*)(ws + 2162688);
  unsigned short* WqT   = (unsigned short*)(ws + 2179072);
  unsigned short* WoutT = (unsigned short*)(ws + 2195456);
  unsigned short* ctxb  = (unsigned short*)(ws + 2457600);
  float* P = ws + 2981888;

  cg::grid_group grid = cg::this_grid();
  const int tid = threadIdx.x;
  const int bid = blockIdx.x;
  __shared__ __align__(16) char smem[16640];

  if (bid < 144)
    ph_transpose(bid, tid, smem, Wctx, Wq, Wout, WctxT, WqT, WoutT);
  __threadfence(); grid.sync(); __threadfence();

  for (int t = bid; t < 528; t += 512) {
    if (t < 272) ph_uhwq(t, tid, smem, mb, input, WctxT, WqT, uhT, wqo);
    else         ph_pre(t - 272, tid, smem, input, WoutT, bout, P);
    __syncthreads();
  }
  __threadfence(); grid.sync(); __threadfence();

  {
    const int virt = (bid & 7) * 64 + (bid >> 3);   // same-n blocks -> same XCD
    ph_scores_pair(virt, tid, smem, uhT, wqo, vvec, alpha_bf, yal_bf);
  }
  __threadfence(); grid.sync(); __threadfence();

  {
    const int virt = (bid & 7) * 64 + (bid >> 3);   // xcd x handles n in {2x,2x+1}
    const int n = virt >> 5, rem = virt & 31;
    ph_ctx(n, (rem >> 1) * 32, rem & 1, tid, smem, alpha_bf, yal_bf, mb, ctxb);
  }
  __threadfence(); grid.sync(); __threadfence();

  ph_out((bid >> 4) * 64, (bid & 15) * 32, tid, smem, ctxb, WoutT, P, out);
}

// ================================================================ fallback kernels
__global__ __launch_bounds__(256) void k_transpose(const float* __restrict__ Wctx,
                                                   const float* __restrict__ Wq,
                                                   const float* __restrict__ Wout,
                                                   unsigned short* __restrict__ WctxT,
                                                   unsigned short* __restrict__ WqT,
                                                   unsigned short* __restrict__ WoutT) {
  __shared__ __align__(16) char smem[16640];
  ph_transpose(blockIdx.x, threadIdx.x, smem, Wctx, Wq, Wout, WctxT, WqT, WoutT);
}

__global__ __launch_bounds__(256) void k_uhwq_pre(const float* __restrict__ mb,
                                                  const float* __restrict__ input,
                                                  const unsigned short* __restrict__ WctxT,
                                                  const unsigned short* __restrict__ WqT,
                                                  const unsigned short* __restrict__ WoutT,
                                                  const float* __restrict__ bout,
                                                  float* __restrict__ uhT,
                                                  float* __restrict__ wqo,
                                                  float* __restrict__ P) {
  __shared__ __align__(16) char smem[8192];
  const int b = blockIdx.x;
  if (b < 272) ph_uhwq(b, threadIdx.x, smem, mb, input, WctxT, WqT, uhT, wqo);
  else         ph_pre(b - 272, threadIdx.x, smem, input, WoutT, bout, P);
}

__global__ __launch_bounds__(256) void k_scores(const float* __restrict__ uhT,
                                                const float* __restrict__ wqo,
                                                const float* __restrict__ vvec,
                                                unsigned short* __restrict__ alpha_bf,
                                                unsigned short* __restrict__ yal_bf) {
  __shared__ __align__(16) char smem[1024];
  ph_scores_pair(blockIdx.x, threadIdx.x, smem, uhT, wqo, vvec, alpha_bf, yal_bf);
}

__global__ __launch_bounds__(256) void k_ctx(const unsigned short* __restrict__ alpha_bf,
                                             const unsigned short* __restrict__ yal_bf,
                                             const float* __restrict__ mb,
                                             unsigned short* __restrict__ ctxb) {
  __shared__ __align__(16) char smem[4096];
  const int x = blockIdx.x;           // n = x&15 -> same-n blocks share an XCD
  ph_ctx(x & 15, ((x >> 4) & 15) * 32, x >> 8, threadIdx.x, smem, alpha_bf, yal_bf, mb, ctxb);
}

__global__ __launch_bounds__(256) void k_out(const unsigned short* __restrict__ ctxb,
                                             const unsigned short* __restrict__ WoutT,
                                             const float* __restrict__ P,
                                             float* __restrict__ out) {
  __shared__ __align__(16) char smem[8192];
  ph_out((blockIdx.x >> 4) * 64, (blockIdx.x & 15) * 32, threadIdx.x, smem, ctxb, WoutT, P, out);
}

// ================================================================ launch
extern "C" void kernel_launch(void* const* d_in, const int* in_sizes, int n_in,
                              void* d_out, int out_size, void* d_ws, size_t ws_size,
                              hipStream_t stream) {
  const float* input = (const float*)d_in[0];   // [16,64,512]
  const float* mb    = (const float*)d_in[1];   // [16,1024,512]
  const float* W_q   = (const float*)d_in[2];   // [512,64]
  const float* W_ctx = (const float*)d_in[3];   // [512,64]
  const float* v     = (const float*)d_in[4];   // [64]
  const float* W_out = (const float*)d_in[5];   // [1024,512]
  const float* b_out = (const float*)d_in[6];   // [512]
  float* out = (float*)d_out;                   // [2,16,64,512]
  float* ws = (float*)d_ws;

  float* uhT = ws;
  float* wqo = ws + 1048576;
  unsigned short* alpha_bf = (unsigned short*)(ws + 1114112);
  unsigned short* yal_bf   = (unsigned short*)(ws + 1638400);
  unsigned short* WctxT = (unsigned short*)(ws + 2162688);
  unsigned short* WqT   = (unsigned short*)(ws + 2179072);
  unsigned short* WoutT = (unsigned short*)(ws + 2195456);
  unsigned short* ctxb  = (unsigned short*)(ws + 2457600);
  float* P = ws + 2981888;

  static int g_coop = -1;   // -1 unknown, 1 proven working, 0 proven broken

  hipStreamCaptureStatus cap = hipStreamCaptureStatusNone;
  (void)hipStreamIsCapturing(stream, &cap);
  const bool capturing = (cap != hipStreamCaptureStatusNone);

  if (g_coop == 1 || (g_coop == -1 && !capturing)) {
    const float* a_input = input; const float* a_mb = mb;
    const float* a_wq = W_q; const float* a_wctx = W_ctx; const float* a_v = v;
    const float* a_wout = W_out; const float* a_bout = b_out;
    float* a_out = out; float* a_ws = ws;
    void* kargs[] = {(void*)&a_input, (void*)&a_mb, (void*)&a_wq, (void*)&a_wctx,
                     (void*)&a_v, (void*)&a_wout, (void*)&a_bout, (void*)&a_out, (void*)&a_ws};
    hipError_t rc = hipLaunchCooperativeKernel((const void*)mega, dim3(512), dim3(256),
                                               kargs, 0, stream);
    if (rc == hipSuccess) { g_coop = 1; return; }
    g_coop = 0;
    (void)hipGetLastError();   // clear sticky error before fallback
  }

  // ---------------- fallback: 5 dispatches ----------------
  k_transpose<<<144, 256, 0, stream>>>(W_ctx, W_q, W_out, WctxT, WqT, WoutT);
  k_uhwq_pre<<<528, 256, 0, stream>>>(mb, input, WctxT, WqT, WoutT, b_out, uhT, wqo, P);
  k_scores<<<512, 256, 0, stream>>>(uhT, wqo, v, alpha_bf, yal_bf);
  k_ctx<<<512, 256, 0, stream>>>(alpha_bf, yal_bf, mb, ctxb);
  k_out<<<512, 256, 0, stream>>>(ctxb, WoutT, P, out);
}

// Round 4
// 147.590 us; speedup vs baseline: 4.7612x; 4.7612x over previous
//
#include <hip/hip_runtime.h>
#include <hip/hip_bf16.h>
#include <stdint.h>

#define DEV __device__ __forceinline__

typedef __attribute__((ext_vector_type(8))) short short8;   // 8 bf16 (4 VGPRs)
typedef __attribute__((ext_vector_type(4))) float f32x4;    // MFMA acc

#define TWO_LOG2E 2.8853900817779268f   // 2*log2(e): exp(2x) == exp2(x*TWO_LOG2E)

// ---------------------------------------------------------------- helpers
DEV unsigned short f2bf(float f) {           // fp32 -> bf16, RNE
  uint32_t u = __float_as_uint(f);
  u += 0x7FFFu + ((u >> 16) & 1u);
  return (unsigned short)(u >> 16);
}

DEV uint2 pk4(float4 f) {                    // 4 fp32 -> 4 bf16 (packed cvt)
  union { __hip_bfloat162 h; unsigned u; } a, b;
  a.h = __float22bfloat162_rn(make_float2(f.x, f.y));
  b.h = __float22bfloat162_rn(make_float2(f.z, f.w));
  return make_uint2(a.u, b.u);
}

DEV short8 mk8(uint2 lo, uint2 hi) {
  union { short8 s; uint4 u; } t;
  t.u = make_uint4(lo.x, lo.y, hi.x, hi.y);
  return t.s;
}

DEV uint32_t rotl32(uint32_t x, int r) { return (x << r) | (x >> (32 - r)); }

// JAX Threefry-2x32 with key = (0, 42)  (jax.random.key(42))
DEV void threefry_0_42(uint32_t x0, uint32_t x1, uint32_t& o0, uint32_t& o1) {
  const uint32_t ks0 = 0u, ks1 = 42u, ks2 = 0x1BD11BDAu ^ 42u;
  x0 += ks0; x1 += ks1;
#define TFR(r) { x0 += x1; x1 = rotl32(x1, (r)); x1 ^= x0; }
  TFR(13) TFR(15) TFR(26) TFR(6)  x0 += ks1; x1 += ks2 + 1u;
  TFR(17) TFR(29) TFR(16) TFR(24) x0 += ks2; x1 += ks0 + 2u;
  TFR(13) TFR(15) TFR(26) TFR(6)  x0 += ks0; x1 += ks1 + 3u;
  TFR(17) TFR(29) TFR(16) TFR(24) x0 += ks1; x1 += ks2 + 4u;
  TFR(13) TFR(15) TFR(26) TFR(6)  x0 += ks2; x1 += ks0 + 5u;
#undef TFR
  o0 = x0; o1 = x1;
}

DEV float wredmax(float v) {
#pragma unroll
  for (int off = 32; off > 0; off >>= 1) v = fmaxf(v, __shfl_xor(v, off));
  return v;
}
DEV float wredsum(float v) {
#pragma unroll
  for (int off = 32; off > 0; off >>= 1) v += __shfl_xor(v, off);
  return v;
}

// ================================================================ prep: weight transposes
DEV void ph_transpose(int b, int tid, char* smem,
                      const float* Wctx, const float* Wq, const float* Wout,
                      unsigned short* WctxT, unsigned short* WqT, unsigned short* WoutT) {
  float (*tile)[65] = (float(*)[65])smem;
  const float* src; unsigned short* dst; int R, C, br, bc;
  if (b < 8)       { src = Wctx; dst = WctxT; R = 512;  C = 64;  br = b * 64;       bc = 0; }
  else if (b < 16) { src = Wq;   dst = WqT;   R = 512;  C = 64;  br = (b - 8) * 64; bc = 0; }
  else { int i = b - 16; src = Wout; dst = WoutT; R = 1024; C = 512; br = (i & 15) * 64; bc = (i >> 4) * 64; }
  const int lr = tid >> 4, lc4 = (tid & 15) * 4;
#pragma unroll
  for (int i = 0; i < 4; ++i) {
    float4 vv = *(const float4*)(src + (long)(br + lr + i * 16) * C + bc + lc4);
    tile[lr + i * 16][lc4 + 0] = vv.x;
    tile[lr + i * 16][lc4 + 1] = vv.y;
    tile[lr + i * 16][lc4 + 2] = vv.z;
    tile[lr + i * 16][lc4 + 3] = vv.w;
  }
  __syncthreads();
#pragma unroll
  for (int i = 0; i < 4; ++i) {
    int crow = lr + i * 16;
    ushort4 o;
    o.x = f2bf(tile[lc4 + 0][crow]);
    o.y = f2bf(tile[lc4 + 1][crow]);
    o.z = f2bf(tile[lc4 + 2][crow]);
    o.w = f2bf(tile[lc4 + 3][crow]);
    *(ushort4*)(dst + (long)(bc + crow) * R + br + lc4) = o;
  }
}

// ================================================================ prep: mb 64x64 tile -> mbT bf16 [n][d=512][s=1024]
DEV void ph_mbtile(int i, int tid, char* smem, const float* mb, unsigned short* mbT) {
  float (*tile)[65] = (float(*)[65])smem;
  const int n = i >> 7, rem = i & 127;
  const int sr0 = (rem >> 3) * 64;          // s base (K of ctx GEMM)
  const int c0 = (rem & 7) * 64;            // src/d base
  const int lr = tid >> 4, lc4 = (tid & 15) * 4;
#pragma unroll
  for (int k = 0; k < 4; ++k) {
    float4 vv = *(const float4*)(mb + ((long)n * 1024 + sr0 + lr + k * 16) * 512 + c0 + lc4);
    tile[lr + k * 16][lc4 + 0] = vv.x;
    tile[lr + k * 16][lc4 + 1] = vv.y;
    tile[lr + k * 16][lc4 + 2] = vv.z;
    tile[lr + k * 16][lc4 + 3] = vv.w;
  }
  __syncthreads();
#pragma unroll
  for (int k = 0; k < 4; ++k) {
    int crow = lr + k * 16;                 // src offset inside tile
    ushort4 o;
    o.x = f2bf(tile[lc4 + 0][crow]);        // same RNE as pk4 did per-iter before
    o.y = f2bf(tile[lc4 + 1][crow]);
    o.z = f2bf(tile[lc4 + 2][crow]);
    o.w = f2bf(tile[lc4 + 3][crow]);
    *(ushort4*)(mbT + (long)n * 524288 + (long)(c0 + crow) * 1024 + sr0 + lc4) = o;
  }
}

// ================================================================ uh / wq GEMM tile (fp32 A via pk4)
DEV void ph_uhwq(int t, int tid, char* smem,
                 const float* mb, const float* input,
                 const unsigned short* WctxT, const unsigned short* WqT,
                 float* uhT, float* wqo) {
  unsigned short (*As)[32] = (unsigned short(*)[32])smem;
  unsigned short (*Bs)[32] = (unsigned short(*)[32])(smem + 4096);
  const float* A; const unsigned short* BT; int mbase;
  if (t < 256) { A = mb;    BT = WctxT; mbase = t * 64; }
  else         { A = input; BT = WqT;   mbase = (t - 256) * 64; }
  const int srow = tid >> 2, kc = tid & 3;
  const int scol = ((kc ^ (srow & 3)) * 8);
  const int wave = tid >> 6, lane = tid & 63;
  const int wm = (wave >> 1) * 32, wn = (wave & 1) * 32;
  const int q = lane >> 4, r = lane & 15;
  const int c0 = ((q ^ (r & 3)) * 8);
  const float* ap = A + (long)(mbase + srow) * 512 + kc * 8;
  const unsigned short* bp = BT + (long)srow * 512 + kc * 8;
  f32x4 acc[2][2];
#pragma unroll
  for (int i = 0; i < 2; ++i)
#pragma unroll
    for (int j = 0; j < 2; ++j) acc[i][j] = (f32x4){0.f, 0.f, 0.f, 0.f};
  float4 fa0 = *(const float4*)(ap);
  float4 fa1 = *(const float4*)(ap + 4);
  uint4 fb = *(const uint4*)(bp);
  for (int k0 = 0; k0 < 512; k0 += 32) {
    uint2 p0 = pk4(fa0), p1 = pk4(fa1);
    *(uint4*)&As[srow][scol] = make_uint4(p0.x, p0.y, p1.x, p1.y);
    *(uint4*)&Bs[srow][scol] = fb;
    __syncthreads();
    if (k0 + 32 < 512) {
      fa0 = *(const float4*)(ap + k0 + 32);
      fa1 = *(const float4*)(ap + k0 + 36);
      fb = *(const uint4*)(bp + k0 + 32);
    }
    short8 a0 = *(const short8*)&As[wm + r][c0];
    short8 a1 = *(const short8*)&As[wm + 16 + r][c0];
    short8 b0 = *(const short8*)&Bs[wn + r][c0];
    short8 b1 = *(const short8*)&Bs[wn + 16 + r][c0];
    acc[0][0] = __builtin_amdgcn_mfma_f32_16x16x32_bf16(a0, b0, acc[0][0], 0, 0, 0);
    acc[0][1] = __builtin_amdgcn_mfma_f32_16x16x32_bf16(a0, b1, acc[0][1], 0, 0, 0);
    acc[1][0] = __builtin_amdgcn_mfma_f32_16x16x32_bf16(a1, b0, acc[1][0], 0, 0, 0);
    acc[1][1] = __builtin_amdgcn_mfma_f32_16x16x32_bf16(a1, b1, acc[1][1], 0, 0, 0);
    __syncthreads();
  }
#pragma unroll
  for (int i2 = 0; i2 < 2; ++i2)
#pragma unroll
    for (int j2 = 0; j2 < 2; ++j2) {
      int gcol = wn + j2 * 16 + r;
      int m = mbase + wm + i2 * 16 + q * 4;
      if (t < 256) {                                   // transposed: uhT[n][d][s]
        int n = m >> 10, s0 = m & 1023;
        float4 o;
        o.x = acc[i2][j2][0] * TWO_LOG2E;
        o.y = acc[i2][j2][1] * TWO_LOG2E;
        o.z = acc[i2][j2][2] * TWO_LOG2E;
        o.w = acc[i2][j2][3] * TWO_LOG2E;
        *(float4*)(uhT + (long)n * 65536 + (long)gcol * 1024 + s0) = o;
      } else {
#pragma unroll
        for (int reg = 0; reg < 4; ++reg)
          wqo[(long)(m + reg) * 64 + gcol] = acc[i2][j2][reg] * TWO_LOG2E;
      }
    }
}

// ================================================================ P = input @ W_top + b
DEV void ph_pre(int tt, int tid, char* smem,
                const float* input, const unsigned short* WoutT,
                const float* bout, float* P) {
  unsigned short (*As)[32] = (unsigned short(*)[32])smem;
  unsigned short (*Bs)[32] = (unsigned short(*)[32])(smem + 4096);
  const int mbase = (tt >> 4) * 64, nbase = (tt & 15) * 32;
  const int srow = tid >> 2, kc = tid & 3;
  const int scol = ((kc ^ (srow & 3)) * 8);
  const int wave = tid >> 6, lane = tid & 63;
  const int wm = (wave >> 1) * 32, wn = (wave & 1) * 16;
  const int q = lane >> 4, r = lane & 15;
  const int c0 = ((q ^ (r & 3)) * 8);
  const float* ap = input + (long)(mbase + srow) * 512 + kc * 8;
  const int brow = (tid & 127) >> 2;
  const unsigned short* bp = WoutT + (long)(nbase + brow) * 1024 + kc * 8;
  f32x4 acc[2];
  acc[0] = (f32x4){0.f, 0.f, 0.f, 0.f};
  acc[1] = (f32x4){0.f, 0.f, 0.f, 0.f};
  float4 fa0 = *(const float4*)(ap);
  float4 fa1 = *(const float4*)(ap + 4);
  uint4 fb;
  if (tid < 128) fb = *(const uint4*)(bp);
  for (int k0 = 0; k0 < 512; k0 += 32) {
    uint2 p0 = pk4(fa0), p1 = pk4(fa1);
    *(uint4*)&As[srow][scol] = make_uint4(p0.x, p0.y, p1.x, p1.y);
    if (tid < 128) *(uint4*)&Bs[brow][(kc ^ (brow & 3)) * 8] = fb;
    __syncthreads();
    int kn = k0 + 32;
    if (kn < 512) {
      fa0 = *(const float4*)(ap + kn);
      fa1 = *(const float4*)(ap + kn + 4);
      if (tid < 128) fb = *(const uint4*)(bp + kn);
    }
    short8 a0 = *(const short8*)&As[wm + r][c0];
    short8 a1 = *(const short8*)&As[wm + 16 + r][c0];
    short8 b0 = *(const short8*)&Bs[wn + r][c0];
    acc[0] = __builtin_amdgcn_mfma_f32_16x16x32_bf16(a0, b0, acc[0], 0, 0, 0);
    acc[1] = __builtin_amdgcn_mfma_f32_16x16x32_bf16(a1, b0, acc[1], 0, 0, 0);
    __syncthreads();
  }
#pragma unroll
  for (int i2 = 0; i2 < 2; ++i2) {
    int gcol = nbase + wn + r;
    float bb = bout[gcol];
#pragma unroll
    for (int reg = 0; reg < 4; ++reg) {
      int grow = mbase + wm + i2 * 16 + q * 4 + reg;
      P[(long)grow * 512 + gcol] = acc[i2][reg] + bb;
    }
  }
}

// ================================================================ scores: softmax + gumbel + writes
DEV void softmax_gumbel_write(float* lsc, int nt, int tid, float* red,
                              unsigned short* alpha_bf, unsigned short* yal_bf) {
  const int wv = tid >> 6, ln = tid & 63;
  float m = fmaxf(fmaxf(lsc[0], lsc[1]), fmaxf(lsc[2], lsc[3]));
  m = wredmax(m);
  if (ln == 0) red[wv] = m;
  __syncthreads();
  m = fmaxf(fmaxf(red[0], red[1]), fmaxf(red[2], red[3]));
  __syncthreads();
  float ss = 0.f;
#pragma unroll
  for (int i = 0; i < 4; ++i) ss += __expf(lsc[i] - m);
  ss = wredsum(ss);
  if (ln == 0) red[wv] = ss;
  __syncthreads();
  ss = red[0] + red[1] + red[2] + red[3];
  const float logl = __logf(ss);
  __syncthreads();

  const uint32_t jbase = (uint32_t)nt * 1024u + (uint32_t)tid * 4u;
  float ys[4];
  float4 av;
#pragma unroll
  for (int i = 0; i < 4; ++i) {
    float la = lsc[i] - m - logl;
    ((float*)&av)[i] = __expf(la);
    uint32_t o0, o1;
    threefry_0_42(0u, jbase + i, o0, o1);
    uint32_t bits = o0 ^ o1;
    float u = __uint_as_float((bits >> 9) | 0x3f800000u) - 1.0f;
    float g = -__logf(-__logf(u + 1e-20f) + 1e-20f);
    ys[i] = (la + g) * 2.0f;                           // /TEMPERATURE (0.5)
  }
  {
    uint2 pa = pk4(av);
    *(uint2*)(alpha_bf + (long)nt * 1024 + tid * 4) = pa;
  }
  float m2 = fmaxf(fmaxf(ys[0], ys[1]), fmaxf(ys[2], ys[3]));
  m2 = wredmax(m2);
  if (ln == 0) red[wv] = m2;
  __syncthreads();
  m2 = fmaxf(fmaxf(red[0], red[1]), fmaxf(red[2], red[3]));
  __syncthreads();
  float s2 = 0.f;
  float4 ye;
#pragma unroll
  for (int i = 0; i < 4; ++i) { ((float*)&ye)[i] = __expf(ys[i] - m2); s2 += ((float*)&ye)[i]; }
  s2 = wredsum(s2);
  if (ln == 0) red[wv] = s2;
  __syncthreads();
  s2 = red[0] + red[1] + red[2] + red[3];
  const float rinv = __fdividef(1.f, s2);
  ye.x *= rinv; ye.y *= rinv; ye.z *= rinv; ye.w *= rinv;
  {
    uint2 py = pk4(ye);
    *(uint2*)(yal_bf + (long)nt * 1024 + tid * 4) = py;
  }
  __syncthreads();   // guard red[] reuse by next invocation
}

DEV void ph_scores_pair(int nt0, int tid, char* smem,
                        const float* uhT, const float* wqo, const float* vvec,
                        unsigned short* alpha_bf, unsigned short* yal_bf) {
  float* wvs0 = (float*)smem;
  float* wvs1 = wvs0 + 64;
  float* vvs  = wvs1 + 64;
  float* red  = vvs + 64;
  const int nt1 = nt0 + 512;
  const int n0 = nt0 >> 6, n1 = nt1 >> 6;
  if (tid < 64) {
    wvs0[tid] = wqo[nt0 * 64 + tid];
    wvs1[tid] = wqo[nt1 * 64 + tid];
    vvs[tid]  = vvec[tid];
  }
  __syncthreads();
  float sumv = 0.f;
#pragma unroll
  for (int d = 0; d < 64; d += 4) {
    float4 vv = *(const float4*)&vvs[d];
    sumv += vv.x + vv.y + vv.z + vv.w;
  }
  const float* un0 = uhT + (long)n0 * 65536 + tid * 4;
  const float* un1 = uhT + (long)n1 * 65536 + tid * 4;
  float4 r0 = make_float4(0.f, 0.f, 0.f, 0.f);
  float4 r1 = make_float4(0.f, 0.f, 0.f, 0.f);
  for (int db = 0; db < 64; db += 4) {
    float4 ua[4], ub[4];
#pragma unroll
    for (int j = 0; j < 4; ++j) {
      ua[j] = *(const float4*)(un0 + (long)(db + j) * 1024);
      ub[j] = *(const float4*)(un1 + (long)(db + j) * 1024);
    }
#pragma unroll
    for (int j = 0; j < 4; ++j) {
      float w0 = wvs0[db + j], w1 = wvs1[db + j], vvj = vvs[db + j];
      r0.x = fmaf(vvj, __builtin_amdgcn_rcpf(1.f + __builtin_amdgcn_exp2f(ua[j].x + w0)), r0.x);
      r0.y = fmaf(vvj, __builtin_amdgcn_rcpf(1.f + __builtin_amdgcn_exp2f(ua[j].y + w0)), r0.y);
      r0.z = fmaf(vvj, __builtin_amdgcn_rcpf(1.f + __builtin_amdgcn_exp2f(ua[j].z + w0)), r0.z);
      r0.w = fmaf(vvj, __builtin_amdgcn_rcpf(1.f + __builtin_amdgcn_exp2f(ua[j].w + w0)), r0.w);
      r1.x = fmaf(vvj, __builtin_amdgcn_rcpf(1.f + __builtin_amdgcn_exp2f(ub[j].x + w1)), r1.x);
      r1.y = fmaf(vvj, __builtin_amdgcn_rcpf(1.f + __builtin_amdgcn_exp2f(ub[j].y + w1)), r1.y);
      r1.z = fmaf(vvj, __builtin_amdgcn_rcpf(1.f + __builtin_amdgcn_exp2f(ub[j].z + w1)), r1.z);
      r1.w = fmaf(vvj, __builtin_amdgcn_rcpf(1.f + __builtin_amdgcn_exp2f(ub[j].w + w1)), r1.w);
    }
  }
  float lsc0[4], lsc1[4];
  lsc0[0] = fmaf(-2.f, r0.x, sumv); lsc0[1] = fmaf(-2.f, r0.y, sumv);
  lsc0[2] = fmaf(-2.f, r0.z, sumv); lsc0[3] = fmaf(-2.f, r0.w, sumv);
  lsc1[0] = fmaf(-2.f, r1.x, sumv); lsc1[1] = fmaf(-2.f, r1.y, sumv);
  lsc1[2] = fmaf(-2.f, r1.z, sumv); lsc1[3] = fmaf(-2.f, r1.w, sumv);
  softmax_gumbel_write(lsc0, nt0, tid, red, alpha_bf, yal_bf);
  softmax_gumbel_write(lsc1, nt1, tid, red, alpha_bf, yal_bf);
}

// ================================================================ ctx tile, fast path: B = mbT bf16 contiguous
DEV void ph_ctx_fast(int n, int dbase, int vt, int tid, char* smem,
                     const unsigned short* alpha_bf, const unsigned short* yal_bf,
                     const unsigned short* mbT, unsigned short* ctxb) {
  unsigned short (*As)[32] = (unsigned short(*)[32])smem;
  const int srow = tid >> 2, kc = tid & 3;
  const int scol = ((kc ^ (srow & 3)) * 8);
  const int wave = tid >> 6, lane = tid & 63;
  const int wm = (wave >> 1) * 32, wn = (wave & 1) * 16;
  const int q = lane >> 4, r = lane & 15;
  const int c0 = ((q ^ (r & 3)) * 8);
  const unsigned short* Ab = (vt ? yal_bf : alpha_bf) + (long)n * 65536 + (long)srow * 1024 + kc * 8;
  const unsigned short* Bb = mbT + (long)n * 524288 + (long)(dbase + wn + r) * 1024 + q * 8;
  f32x4 acc[2];
  acc[0] = (f32x4){0.f, 0.f, 0.f, 0.f};
  acc[1] = (f32x4){0.f, 0.f, 0.f, 0.f};
  uint4 fa  = *(const uint4*)(Ab);
  uint4 fb0 = *(const uint4*)(Bb);          // k-step 0
  uint4 fb1 = *(const uint4*)(Bb + 32);     // k-step 1 (2-deep prefetch)
  for (int k0 = 0; k0 < 1024; k0 += 32) {
    *(uint4*)&As[srow][scol] = fa;
    __syncthreads();
    union { uint4 u; short8 s; } bu; bu.u = fb0;
    if (k0 + 32 < 1024) fa = *(const uint4*)(Ab + k0 + 32);
    fb0 = fb1;
    if (k0 + 64 < 1024) fb1 = *(const uint4*)(Bb + k0 + 64);
    short8 a0 = *(const short8*)&As[wm + r][c0];
    short8 a1 = *(const short8*)&As[wm + 16 + r][c0];
    acc[0] = __builtin_amdgcn_mfma_f32_16x16x32_bf16(a0, bu.s, acc[0], 0, 0, 0);
    acc[1] = __builtin_amdgcn_mfma_f32_16x16x32_bf16(a1, bu.s, acc[1], 0, 0, 0);
    __syncthreads();
  }
#pragma unroll
  for (int i2 = 0; i2 < 2; ++i2) {
    int gcol = dbase + wn + r;
#pragma unroll
    for (int reg = 0; reg < 4; ++reg) {
      long grow = (long)vt * 1024 + n * 64 + wm + i2 * 16 + q * 4 + reg;
      ctxb[grow * 512 + gcol] = f2bf(acc[i2][reg]);
    }
  }
}

// ================================================================ ctx tile, legacy path: B = mb fp32 strided
DEV void ph_ctx_legacy(int n, int dbase, int vt, int tid, char* smem,
                       const unsigned short* alpha_bf, const unsigned short* yal_bf,
                       const float* mb, unsigned short* ctxb) {
  unsigned short (*As)[32] = (unsigned short(*)[32])smem;
  const int srow = tid >> 2, kc = tid & 3;
  const int scol = ((kc ^ (srow & 3)) * 8);
  const int wave = tid >> 6, lane = tid & 63;
  const int wm = (wave >> 1) * 32, wn = (wave & 1) * 16;
  const int q = lane >> 4, r = lane & 15;
  const int c0 = ((q ^ (r & 3)) * 8);
  const unsigned short* Ab = (vt ? yal_bf : alpha_bf) + (long)n * 65536 + (long)srow * 1024 + kc * 8;
  const float* bcol = mb + (long)n * 524288 + dbase + wn + r;
  f32x4 acc[2];
  acc[0] = (f32x4){0.f, 0.f, 0.f, 0.f};
  acc[1] = (f32x4){0.f, 0.f, 0.f, 0.f};
  uint4 fa = *(const uint4*)(Ab);
  float bv[8];
#pragma unroll
  for (int j = 0; j < 8; ++j) bv[j] = bcol[(long)(q * 8 + j) * 512];
  for (int k0 = 0; k0 < 1024; k0 += 32) {
    *(uint4*)&As[srow][scol] = fa;
    __syncthreads();
    float4 blo = make_float4(bv[0], bv[1], bv[2], bv[3]);
    float4 bhi = make_float4(bv[4], bv[5], bv[6], bv[7]);
    short8 b0 = mk8(pk4(blo), pk4(bhi));
    if (k0 + 32 < 1024) {
      fa = *(const uint4*)(Ab + k0 + 32);
#pragma unroll
      for (int j = 0; j < 8; ++j) bv[j] = bcol[(long)(k0 + 32 + q * 8 + j) * 512];
    }
    short8 a0 = *(const short8*)&As[wm + r][c0];
    short8 a1 = *(const short8*)&As[wm + 16 + r][c0];
    acc[0] = __builtin_amdgcn_mfma_f32_16x16x32_bf16(a0, b0, acc[0], 0, 0, 0);
    acc[1] = __builtin_amdgcn_mfma_f32_16x16x32_bf16(a1, b0, acc[1], 0, 0, 0);
    __syncthreads();
  }
#pragma unroll
  for (int i2 = 0; i2 < 2; ++i2) {
    int gcol = dbase + wn + r;
#pragma unroll
    for (int reg = 0; reg < 4; ++reg) {
      long grow = (long)vt * 1024 + n * 64 + wm + i2 * 16 + q * 4 + reg;
      ctxb[grow * 512 + gcol] = f2bf(acc[i2][reg]);
    }
  }
}

// ================================================================ out tile
DEV void ph_out(int mbase, int nbase, int tid, char* smem,
                const unsigned short* ctxb, const unsigned short* WoutT,
                const float* P, float* out) {
  unsigned short (*As)[32] = (unsigned short(*)[32])smem;
  unsigned short (*Bs)[32] = (unsigned short(*)[32])(smem + 4096);
  const int srow = tid >> 2, kc = tid & 3;
  const int scol = ((kc ^ (srow & 3)) * 8);
  const int wave = tid >> 6, lane = tid & 63;
  const int wm = (wave >> 1) * 32, wn = (wave & 1) * 16;
  const int q = lane >> 4, r = lane & 15;
  const int c0 = ((q ^ (r & 3)) * 8);
  const unsigned short* ap = ctxb + (long)(mbase + srow) * 512 + kc * 8;
  const int brow = (tid & 127) >> 2;
  const unsigned short* bp = WoutT + (long)(nbase + brow) * 1024 + 512 + kc * 8;
  f32x4 acc[2];
#pragma unroll
  for (int i2 = 0; i2 < 2; ++i2) {
    int pcol = nbase + wn + r;
#pragma unroll
    for (int reg = 0; reg < 4; ++reg) {
      int prow = (mbase + wm + i2 * 16 + q * 4 + reg) & 1023;
      acc[i2][reg] = P[(long)prow * 512 + pcol];
    }
  }
  uint4 fa = *(const uint4*)(ap);
  uint4 fb;
  if (tid < 128) fb = *(const uint4*)(bp);
  for (int k0 = 0; k0 < 512; k0 += 32) {
    *(uint4*)&As[srow][scol] = fa;
    if (tid < 128) *(uint4*)&Bs[brow][(kc ^ (brow & 3)) * 8] = fb;
    __syncthreads();
    int kn = k0 + 32;
    if (kn < 512) {
      fa = *(const uint4*)(ap + kn);
      if (tid < 128) fb = *(const uint4*)(bp + kn);
    }
    short8 a0 = *(const short8*)&As[wm + r][c0];
    short8 a1 = *(const short8*)&As[wm + 16 + r][c0];
    short8 b0 = *(const short8*)&Bs[wn + r][c0];
    acc[0] = __builtin_amdgcn_mfma_f32_16x16x32_bf16(a0, b0, acc[0], 0, 0, 0);
    acc[1] = __builtin_amdgcn_mfma_f32_16x16x32_bf16(a1, b0, acc[1], 0, 0, 0);
    __syncthreads();
  }
#pragma unroll
  for (int i2 = 0; i2 < 2; ++i2) {
    int gcol = nbase + wn + r;
#pragma unroll
    for (int reg = 0; reg < 4; ++reg) {
      int grow = mbase + wm + i2 * 16 + q * 4 + reg;
      float z = acc[i2][reg];
      float rc = __builtin_amdgcn_rcpf(1.f + __builtin_amdgcn_exp2f(z * TWO_LOG2E));
      out[(long)grow * 512 + gcol] = fmaf(-2.f, rc, 1.f);
    }
  }
}

// ================================================================ kernels
__global__ __launch_bounds__(256) void k_prep(const float* __restrict__ Wctx,
                                              const float* __restrict__ Wq,
                                              const float* __restrict__ Wout,
                                              const float* __restrict__ mb,
                                              unsigned short* __restrict__ WctxT,
                                              unsigned short* __restrict__ WqT,
                                              unsigned short* __restrict__ WoutT,
                                              unsigned short* __restrict__ mbT) {
  __shared__ __align__(16) char smem[16640];
  const int b = blockIdx.x;
  if (b < 144) ph_transpose(b, threadIdx.x, smem, Wctx, Wq, Wout, WctxT, WqT, WoutT);
  else         ph_mbtile(b - 144, threadIdx.x, smem, mb, mbT);
}

__global__ __launch_bounds__(256) void k_uhwq_pre(const float* __restrict__ mb,
                                                  const float* __restrict__ input,
                                                  const unsigned short* __restrict__ WctxT,
                                                  const unsigned short* __restrict__ WqT,
                                                  const unsigned short* __restrict__ WoutT,
                                                  const float* __restrict__ bout,
                                                  float* __restrict__ uhT,
                                                  float* __restrict__ wqo,
                                                  float* __restrict__ P) {
  __shared__ __align__(16) char smem[8192];
  const int b = blockIdx.x;
  if (b < 272) ph_uhwq(b, threadIdx.x, smem, mb, input, WctxT, WqT, uhT, wqo);
  else         ph_pre(b - 272, threadIdx.x, smem, input, WoutT, bout, P);
}

__global__ __launch_bounds__(256) void k_scores(const float* __restrict__ uhT,
                                                const float* __restrict__ wqo,
                                                const float* __restrict__ vvec,
                                                unsigned short* __restrict__ alpha_bf,
                                                unsigned short* __restrict__ yal_bf) {
  __shared__ __align__(16) char smem[1024];
  ph_scores_pair(blockIdx.x, threadIdx.x, smem, uhT, wqo, vvec, alpha_bf, yal_bf);
}

__global__ __launch_bounds__(256) void k_ctx_fast(const unsigned short* __restrict__ alpha_bf,
                                                  const unsigned short* __restrict__ yal_bf,
                                                  const unsigned short* __restrict__ mbT,
                                                  unsigned short* __restrict__ ctxb) {
  __shared__ __align__(16) char smem[4096];
  const int x = blockIdx.x;           // n = x&15 -> same-n blocks share an XCD
  ph_ctx_fast(x & 15, ((x >> 4) & 15) * 32, x >> 8, threadIdx.x, smem, alpha_bf, yal_bf, mbT, ctxb);
}

__global__ __launch_bounds__(256) void k_ctx_legacy(const unsigned short* __restrict__ alpha_bf,
                                                    const unsigned short* __restrict__ yal_bf,
                                                    const float* __restrict__ mb,
                                                    unsigned short* __restrict__ ctxb) {
  __shared__ __align__(16) char smem[4096];
  const int x = blockIdx.x;
  ph_ctx_legacy(x & 15, ((x >> 4) & 15) * 32, x >> 8, threadIdx.x, smem, alpha_bf, yal_bf, mb, ctxb);
}

__global__ __launch_bounds__(256) void k_out(const unsigned short* __restrict__ ctxb,
                                             const unsigned short* __restrict__ WoutT,
                                             const float* __restrict__ P,
                                             float* __restrict__ out) {
  __shared__ __align__(16) char smem[8192];
  ph_out((blockIdx.x >> 4) * 64, (blockIdx.x & 15) * 32, threadIdx.x, smem, ctxb, WoutT, P, out);
}

// ================================================================ launch
// ws layout (float units):
//   uhT      [0       , 1048576)   fp32 [16][64][1024] TRANSPOSED, prescaled
//   wqo      [1048576 , 1114112)   fp32 [1024][64], prescaled
//   alpha_bf [1114112 , 1638400)   bf16 [16][64][1024]
//   yal_bf   [1638400 , 2162688)   bf16 [16][64][1024]
//   WctxT    [2162688 , 2179072)   bf16 [64][512]
//   WqT      [2179072 , 2195456)   bf16 [64][512]
//   WoutT    [2195456 , 2457600)   bf16 [512][1024]
//   ctxb     [2457600 , 2981888)   bf16 [2048][512]
//   P        [2981888 , 3506176)   fp32 [1024][512]
//   mbT      [3506176 , 7700480)   bf16 [16][512][1024]  (only if ws_size permits)
extern "C" void kernel_launch(void* const* d_in, const int* in_sizes, int n_in,
                              void* d_out, int out_size, void* d_ws, size_t ws_size,
                              hipStream_t stream) {
  const float* input = (const float*)d_in[0];   // [16,64,512]
  const float* mb    = (const float*)d_in[1];   // [16,1024,512]
  const float* W_q   = (const float*)d_in[2];   // [512,64]
  const float* W_ctx = (const float*)d_in[3];   // [512,64]
  const float* v     = (const float*)d_in[4];   // [64]
  const float* W_out = (const float*)d_in[5];   // [1024,512]
  const float* b_out = (const float*)d_in[6];   // [512]
  float* out = (float*)d_out;                   // [2,16,64,512]
  float* ws = (float*)d_ws;

  float* uhT = ws;
  float* wqo = ws + 1048576;
  unsigned short* alpha_bf = (unsigned short*)(ws + 1114112);
  unsigned short* yal_bf   = (unsigned short*)(ws + 1638400);
  unsigned short* WctxT = (unsigned short*)(ws + 2162688);
  unsigned short* WqT   = (unsigned short*)(ws + 2179072);
  unsigned short* WoutT = (unsigned short*)(ws + 2195456);
  unsigned short* ctxb  = (unsigned short*)(ws + 2457600);
  float* P = ws + 2981888;
  unsigned short* mbT = (unsigned short*)(ws + 3506176);

  const bool big = ws_size >= (size_t)7700480 * 4;

  k_prep<<<big ? 2192 : 144, 256, 0, stream>>>(W_ctx, W_q, W_out, mb, WctxT, WqT, WoutT, mbT);
  k_uhwq_pre<<<528, 256, 0, stream>>>(mb, input, WctxT, WqT, WoutT, b_out, uhT, wqo, P);
  k_scores<<<512, 256, 0, stream>>>(uhT, wqo, v, alpha_bf, yal_bf);
  if (big) k_ctx_fast<<<512, 256, 0, stream>>>(alpha_bf, yal_bf, mbT, ctxb);
  else     k_ctx_legacy<<<512, 256, 0, stream>>>(alpha_bf, yal_bf, mb, ctxb);
  k_out<<<512, 256, 0, stream>>>(ctxb, WoutT, P, out);
}